// Round 1
// baseline (132.058 us; speedup 1.0000x reference)
//
#include <hip/hip_runtime.h>
#include <math.h>

#define BB 16
#define NN 2048
#define MM 16
#define SS 128

__constant__ const float kFourPi = 12.566370614359172f;

// One block per (b,m). Computes:
//   d1[b,n,m]  = min_s ||P[b,m,s] - Q[b,n,m]||^2   (written to ws)
//   d2sum[b,m] = sum_s clamp(min_n dist)           (one scalar per block)
__global__ __launch_bounds__(256) void dist_kernel(
    const float* __restrict__ pcl,    // (B,N,M,3)
    const float* __restrict__ prim,   // (B,M,S,3)
    float* __restrict__ d1,           // (B,N,M)
    float* __restrict__ d2sum)        // (B*M)
{
    const int bm  = blockIdx.x;
    const int b   = bm >> 4;
    const int m   = bm & 15;
    const int tid = threadIdx.x;

    __shared__ float Px[SS], Py[SS], Pz[SS];
    __shared__ float wmin[4][SS];
    __shared__ float ssum[4];

    // stage primitive points (128 x 3) into LDS, SoA
    const float* pp = prim + (size_t)bm * SS * 3;
    if (tid < SS) {
        Px[tid] = pp[tid * 3 + 0];
        Py[tid] = pp[tid * 3 + 1];
        Pz[tid] = pp[tid * 3 + 2];
    }

    // each thread owns 8 pcl points: n = tid + j*256 (held in registers all pass)
    float qx[8], qy[8], qz[8];
#pragma unroll
    for (int j = 0; j < 8; ++j) {
        const int n = tid + j * 256;
        const float* q = pcl + ((size_t)(b * NN + n) * MM + m) * 3;
        qx[j] = q[0]; qy[j] = q[1]; qz[j] = q[2];
    }
    __syncthreads();

    float d1min[8];
#pragma unroll
    for (int j = 0; j < 8; ++j) d1min[j] = 3.0e38f;

    const int wid  = tid >> 6;
    const int lane = tid & 63;

    for (int s = 0; s < SS; ++s) {
        const float px = Px[s], py = Py[s], pz = Pz[s];  // LDS broadcast
        float lmin = 3.0e38f;
#pragma unroll
        for (int j = 0; j < 8; ++j) {
            const float dx = px - qx[j];
            const float dy = py - qy[j];
            const float dz = pz - qz[j];
            float d = dx * dx;
            d = fmaf(dy, dy, d);
            d = fmaf(dz, dz, d);
            d1min[j] = fminf(d1min[j], d);
            lmin     = fminf(lmin, d);
        }
        // wave min-reduce (64 lanes)
#pragma unroll
        for (int off = 32; off > 0; off >>= 1)
            lmin = fminf(lmin, __shfl_down(lmin, off, 64));
        if (lane == 0) wmin[wid][s] = lmin;
    }

    // write d1 (strided by M, coalesced within consecutive tid for fixed j? stride 16 floats — acceptable, traffic is 2 MB total)
#pragma unroll
    for (int j = 0; j < 8; ++j) {
        const int n = tid + j * 256;
        d1[(size_t)(b * NN + n) * MM + m] = d1min[j];
    }

    __syncthreads();
    // finalize d2: threads 0..127 combine the 4 wave partials for their s, clamp, then block-sum
    float v = 0.0f;
    if (tid < SS) {
        v = fminf(fminf(wmin[0][tid], wmin[1][tid]),
                  fminf(wmin[2][tid], wmin[3][tid]));
        if (v >= 1.0e30f) v = 0.0f;
    }
#pragma unroll
    for (int off = 32; off > 0; off >>= 1)
        v += __shfl_down(v, off, 64);
    if (lane == 0) ssum[wid] = v;
    __syncthreads();
    if (tid == 0) d2sum[bm] = ssum[0] + ssum[1] + ssum[2] + ssum[3];
}

// One thread per (b,n): sort 16 (dist,prob) pairs, stick-breaking weighted sum.
__global__ __launch_bounds__(256) void p2p_kernel(
    const float* __restrict__ d1,     // (B*N, M) contiguous
    const float* __restrict__ probs,  // (B, M)
    float* __restrict__ partial)      // (gridDim.x)
{
    const int gid = blockIdx.x * 256 + threadIdx.x;  // == b*N + n
    const int b   = gid >> 11;                       // / N

    float d[16], p[16];
    const float4* dp = (const float4*)(d1 + (size_t)gid * 16);
    float4 v;
    v = dp[0]; d[0]  = v.x; d[1]  = v.y; d[2]  = v.z; d[3]  = v.w;
    v = dp[1]; d[4]  = v.x; d[5]  = v.y; d[6]  = v.z; d[7]  = v.w;
    v = dp[2]; d[8]  = v.x; d[9]  = v.y; d[10] = v.z; d[11] = v.w;
    v = dp[3]; d[12] = v.x; d[13] = v.y; d[14] = v.z; d[15] = v.w;

    const float* pb = probs + b * 16;
#pragma unroll
    for (int k = 0; k < 16; ++k) p[k] = pb[k];

    // odd-even transposition sort, 16 rounds — fully static register indices
#define CE(i, j)                                              \
    {                                                         \
        const bool c = d[i] > d[j];                           \
        const float td = c ? d[j] : d[i];                     \
        d[j] = c ? d[i] : d[j];  d[i] = td;                   \
        const float tp = c ? p[j] : p[i];                     \
        p[j] = c ? p[i] : p[j];  p[i] = tp;                   \
    }
#pragma unroll
    for (int r = 0; r < 16; ++r) {
        if ((r & 1) == 0) {
            CE(0, 1) CE(2, 3) CE(4, 5) CE(6, 7)
            CE(8, 9) CE(10, 11) CE(12, 13) CE(14, 15)
        } else {
            CE(1, 2) CE(3, 4) CE(5, 6) CE(7, 8)
            CE(9, 10) CE(11, 12) CE(13, 14)
        }
    }
#undef CE

    float acc = 1.0f, sum = 0.0f;
#pragma unroll
    for (int k = 0; k < 16; ++k) {
        sum += d[k] * p[k] * acc;
        acc *= (1.0f - p[k]);
    }

    // block reduce sum
    const int wid  = threadIdx.x >> 6;
    const int lane = threadIdx.x & 63;
    __shared__ float red[4];
#pragma unroll
    for (int off = 32; off > 0; off >>= 1)
        sum += __shfl_down(sum, off, 64);
    if (lane == 0) red[wid] = sum;
    __syncthreads();
    if (threadIdx.x == 0)
        partial[blockIdx.x] = red[0] + red[1] + red[2] + red[3];
}

// Single block: area weighting + final double-precision combines.
__global__ __launch_bounds__(256) void final_kernel(
    const float* __restrict__ size_,   // (B,M,3)
    const float* __restrict__ probs,   // (B,M)
    const float* __restrict__ d2sum,   // (B*M)
    const float* __restrict__ partial, // (128)
    float* __restrict__ out)           // (4)
{
    const int tid = threadIdx.x;       // == b*16 + m
    const int b   = tid >> 4;

    __shared__ float  areaSh[256];
    __shared__ double redA[4];
    __shared__ double redB[4];

    const float s0 = size_[tid * 3 + 0];
    const float s1 = size_[tid * 3 + 1];
    const float s2 = size_[tid * 3 + 2];
    const float inner = powf(s0 * s1, 1.6f) * (1.0f / 3.0f)
                      + powf(s0 * s2, 1.6f) * (1.0f / 3.0f)
                      + powf(s1 * s2, 1.6f) * (1.0f / 3.0f);
    const float a = kFourPi * powf(inner, 0.625f);
    areaSh[tid] = a;
    __syncthreads();

    float asum = 0.0f;
#pragma unroll
    for (int mm = 0; mm < 16; ++mm) asum += areaSh[b * 16 + mm];
    const float anorm = 16.0f * a / asum;  // M * area / sum_m area

    const int wid  = tid >> 6;
    const int lane = tid & 63;

    // prim_to_pcl terms: mean_s(d2) * probs * anorm
    double t = (double)(d2sum[tid] * (1.0f / 128.0f)) * (double)probs[tid] * (double)anorm;
#pragma unroll
    for (int off = 32; off > 0; off >>= 1)
        t += __shfl_down(t, off, 64);
    if (lane == 0) redA[wid] = t;

    // pcl_to_prim partials (128 of them)
    double u = (tid < 128) ? (double)partial[tid] : 0.0;
#pragma unroll
    for (int off = 32; off > 0; off >>= 1)
        u += __shfl_down(u, off, 64);
    if (lane == 0) redB[wid] = u;

    __syncthreads();
    if (tid == 0) {
        const double prim_to_pcl = (redA[0] + redA[1] + redA[2] + redA[3]) / 256.0;    // / (B*M)
        const double pcl_to_prim = (redB[0] + redB[1] + redB[2] + redB[3]) / 32768.0;  // / (B*N)
        const double total = pcl_to_prim + prim_to_pcl;
        out[0] = (float)total;
        out[1] = (float)pcl_to_prim;
        out[2] = (float)prim_to_pcl;
        out[3] = 0.0f;
    }
}

extern "C" void kernel_launch(void* const* d_in, const int* in_sizes, int n_in,
                              void* d_out, int out_size, void* d_ws, size_t ws_size,
                              hipStream_t stream) {
    const float* pcl   = (const float*)d_in[0];  // (B,N,M,3)
    const float* prim  = (const float*)d_in[1];  // (B,M,S,3)
    const float* size_ = (const float*)d_in[2];  // (B,M,3)
    const float* probs = (const float*)d_in[3];  // (B,M)
    float* out = (float*)d_out;

    float* d1      = (float*)d_ws;                  // B*N*M = 524288 floats (2 MiB)
    float* d2sum   = d1 + (size_t)BB * NN * MM;     // 256 floats
    float* partial = d2sum + BB * MM;               // 128 floats

    dist_kernel<<<BB * MM, 256, 0, stream>>>(pcl, prim, d1, d2sum);
    p2p_kernel<<<(BB * NN) / 256, 256, 0, stream>>>(d1, probs, partial);
    final_kernel<<<1, 256, 0, stream>>>(size_, probs, d2sum, partial, out);
}

// Round 2
// 94.282 us; speedup vs baseline: 1.4007x; 1.4007x over previous
//
#include <hip/hip_runtime.h>
#include <math.h>

#define BB 16
#define NN 2048
#define MM 16
#define SS 128

__constant__ const float kFourPi = 12.566370614359172f;

// ---------------------------------------------------------------------------
// FAST PATH
// ---------------------------------------------------------------------------

// Tiled transpose: pcl (B,N,M,3) -> SoA pclX/pclY/pclZ [b*16+m][n]
__global__ __launch_bounds__(256) void transpose_kernel(
    const float* __restrict__ pcl,
    float* __restrict__ pclX, float* __restrict__ pclY, float* __restrict__ pclZ)
{
    const int b  = blockIdx.x;          // 16
    const int n0 = blockIdx.y * 128;    // 16 chunks of 128 n
    __shared__ float q[6144];           // 128 n x 16 m x 3 c

    const float4* src = (const float4*)(pcl + ((size_t)b * NN + n0) * (MM * 3));
    float4* qv = (float4*)q;
#pragma unroll
    for (int k = 0; k < 6; ++k)
        qv[threadIdx.x + k * 256] = src[threadIdx.x + k * 256];
    __syncthreads();

#pragma unroll
    for (int k = 0; k < 24; ++k) {
        const int e = threadIdx.x + k * 256;
        const int m = e / 384;
        const int r = e - m * 384;
        const int c = r >> 7;
        const int n = r & 127;
        const float v = q[(n * 16 + m) * 3 + c];
        float* dst = (c == 0) ? pclX : ((c == 1) ? pclY : pclZ);
        dst[((size_t)(b * MM + m)) * NN + n0 + n] = v;
    }
}

// grid (256 bm, 4 s-chunks). Each block: all N=2048 (8 n/thread in regs),
// 32 s from LDS. Writes d1part[cs][bm][n] (dense) and d2part[cs][bm].
__global__ __launch_bounds__(256) void dist2_kernel(
    const float* __restrict__ pclX, const float* __restrict__ pclY,
    const float* __restrict__ pclZ, const float* __restrict__ prim,
    float* __restrict__ d1part,   // [4][256][2048]
    float* __restrict__ d2part)   // [4][256]
{
    const int bm  = blockIdx.x;
    const int cs  = blockIdx.y;
    const int tid = threadIdx.x;
    const int s0  = cs * 32;

    __shared__ float Px[32], Py[32], Pz[32];
    __shared__ float wmin[4][32];

    const float* pp = prim + ((size_t)bm * SS + s0) * 3;
    if (tid < 32) {
        Px[tid] = pp[tid * 3 + 0];
        Py[tid] = pp[tid * 3 + 1];
        Pz[tid] = pp[tid * 3 + 2];
    }

    const size_t qbase = (size_t)bm * NN + tid;
    float qx[8], qy[8], qz[8];
#pragma unroll
    for (int j = 0; j < 8; ++j) {
        qx[j] = pclX[qbase + j * 256];
        qy[j] = pclY[qbase + j * 256];
        qz[j] = pclZ[qbase + j * 256];
    }
    __syncthreads();

    float d1min[8];
#pragma unroll
    for (int j = 0; j < 8; ++j) d1min[j] = 3.0e38f;

    const int wid  = tid >> 6;
    const int lane = tid & 63;

#pragma unroll 4
    for (int s = 0; s < 32; ++s) {
        const float px = Px[s], py = Py[s], pz = Pz[s];
        float lmin = 3.0e38f;
#pragma unroll
        for (int j = 0; j < 8; ++j) {
            const float dx = px - qx[j];
            const float dy = py - qy[j];
            const float dz = pz - qz[j];
            float d = dx * dx;
            d = fmaf(dy, dy, d);
            d = fmaf(dz, dz, d);
            d1min[j] = fminf(d1min[j], d);
            lmin     = fminf(lmin, d);
        }
#pragma unroll
        for (int off = 32; off > 0; off >>= 1)
            lmin = fminf(lmin, __shfl_down(lmin, off, 64));
        if (lane == 0) wmin[wid][s] = lmin;
    }

    float* dd = d1part + ((size_t)(cs * 256 + bm)) * NN + tid;
#pragma unroll
    for (int j = 0; j < 8; ++j) dd[j * 256] = d1min[j];

    __syncthreads();
    float v = 0.0f;
    if (tid < 32) {
        v = fminf(fminf(wmin[0][tid], wmin[1][tid]),
                  fminf(wmin[2][tid], wmin[3][tid]));
        if (v >= 1.0e30f) v = 0.0f;
    }
#pragma unroll
    for (int off = 32; off > 0; off >>= 1)
        v += __shfl_down(v, off, 64);
    if (tid == 0) d2part[cs * 256 + bm] = v;
}

// One thread per (b,n): 4-way min over s-chunks (coalesced loads), sort 16,
// stick-breaking weighted sum, block partial.
__global__ __launch_bounds__(128) void p2p2_kernel(
    const float* __restrict__ d1part,  // [4][256][2048]
    const float* __restrict__ probs,   // (B,M)
    float* __restrict__ partial)       // [256]
{
    const int gid = blockIdx.x * 128 + threadIdx.x;  // b*N + n
    const int b   = gid >> 11;
    const int n   = gid & (NN - 1);

    float d[16], p[16];
#pragma unroll
    for (int m = 0; m < 16; ++m) {
        const size_t base = ((size_t)(b * MM + m)) * NN + n;
        const float v0 = d1part[base];
        const float v1 = d1part[base + (size_t)256 * NN];
        const float v2 = d1part[base + (size_t)512 * NN];
        const float v3 = d1part[base + (size_t)768 * NN];
        d[m] = fminf(fminf(v0, v1), fminf(v2, v3));
    }

    const float* pb = probs + b * MM;
#pragma unroll
    for (int k = 0; k < 16; ++k) p[k] = pb[k];

#define CE(i, j)                                              \
    {                                                         \
        const bool c = d[i] > d[j];                           \
        const float td = c ? d[j] : d[i];                     \
        d[j] = c ? d[i] : d[j];  d[i] = td;                   \
        const float tp = c ? p[j] : p[i];                     \
        p[j] = c ? p[i] : p[j];  p[i] = tp;                   \
    }
#pragma unroll
    for (int r = 0; r < 16; ++r) {
        if ((r & 1) == 0) {
            CE(0, 1) CE(2, 3) CE(4, 5) CE(6, 7)
            CE(8, 9) CE(10, 11) CE(12, 13) CE(14, 15)
        } else {
            CE(1, 2) CE(3, 4) CE(5, 6) CE(7, 8)
            CE(9, 10) CE(11, 12) CE(13, 14)
        }
    }
#undef CE

    float acc = 1.0f, sum = 0.0f;
#pragma unroll
    for (int k = 0; k < 16; ++k) {
        sum += d[k] * p[k] * acc;
        acc *= (1.0f - p[k]);
    }

    const int wid  = threadIdx.x >> 6;
    const int lane = threadIdx.x & 63;
    __shared__ float red[2];
#pragma unroll
    for (int off = 32; off > 0; off >>= 1)
        sum += __shfl_down(sum, off, 64);
    if (lane == 0) red[wid] = sum;
    __syncthreads();
    if (threadIdx.x == 0) partial[blockIdx.x] = red[0] + red[1];
}

__global__ __launch_bounds__(256) void final2_kernel(
    const float* __restrict__ size_,   // (B,M,3)
    const float* __restrict__ probs,   // (B,M)
    const float* __restrict__ d2part,  // [4][256]
    const float* __restrict__ partial, // [256]
    float* __restrict__ out)           // (4)
{
    const int tid = threadIdx.x;       // b*16 + m
    const int b   = tid >> 4;

    __shared__ float  areaSh[256];
    __shared__ double redA[4];
    __shared__ double redB[4];

    const float s0 = size_[tid * 3 + 0];
    const float s1 = size_[tid * 3 + 1];
    const float s2 = size_[tid * 3 + 2];
    const float inner = powf(s0 * s1, 1.6f) * (1.0f / 3.0f)
                      + powf(s0 * s2, 1.6f) * (1.0f / 3.0f)
                      + powf(s1 * s2, 1.6f) * (1.0f / 3.0f);
    const float a = kFourPi * powf(inner, 0.625f);
    areaSh[tid] = a;
    __syncthreads();

    float asum = 0.0f;
#pragma unroll
    for (int mm = 0; mm < 16; ++mm) asum += areaSh[b * 16 + mm];
    const float anorm = 16.0f * a / asum;

    const int wid  = tid >> 6;
    const int lane = tid & 63;

    const float d2s = d2part[tid] + d2part[256 + tid] + d2part[512 + tid] + d2part[768 + tid];
    double t = (double)(d2s * (1.0f / 128.0f)) * (double)probs[tid] * (double)anorm;
#pragma unroll
    for (int off = 32; off > 0; off >>= 1)
        t += __shfl_down(t, off, 64);
    if (lane == 0) redA[wid] = t;

    double u = (double)partial[tid];
#pragma unroll
    for (int off = 32; off > 0; off >>= 1)
        u += __shfl_down(u, off, 64);
    if (lane == 0) redB[wid] = u;

    __syncthreads();
    if (tid == 0) {
        const double prim_to_pcl = (redA[0] + redA[1] + redA[2] + redA[3]) / 256.0;
        const double pcl_to_prim = (redB[0] + redB[1] + redB[2] + redB[3]) / 32768.0;
        out[0] = (float)(pcl_to_prim + prim_to_pcl);
        out[1] = (float)pcl_to_prim;
        out[2] = (float)prim_to_pcl;
        out[3] = 0.0f;
    }
}

// ---------------------------------------------------------------------------
// FALLBACK PATH (round-1, works in ~2.1 MB scratch)
// ---------------------------------------------------------------------------

__global__ __launch_bounds__(256) void dist_kernel(
    const float* __restrict__ pcl, const float* __restrict__ prim,
    float* __restrict__ d1, float* __restrict__ d2sum)
{
    const int bm  = blockIdx.x;
    const int b   = bm >> 4;
    const int m   = bm & 15;
    const int tid = threadIdx.x;

    __shared__ float Px[SS], Py[SS], Pz[SS];
    __shared__ float wmin[4][SS];
    __shared__ float ssum[4];

    const float* pp = prim + (size_t)bm * SS * 3;
    if (tid < SS) {
        Px[tid] = pp[tid * 3 + 0];
        Py[tid] = pp[tid * 3 + 1];
        Pz[tid] = pp[tid * 3 + 2];
    }

    float qx[8], qy[8], qz[8];
#pragma unroll
    for (int j = 0; j < 8; ++j) {
        const int n = tid + j * 256;
        const float* q = pcl + ((size_t)(b * NN + n) * MM + m) * 3;
        qx[j] = q[0]; qy[j] = q[1]; qz[j] = q[2];
    }
    __syncthreads();

    float d1min[8];
#pragma unroll
    for (int j = 0; j < 8; ++j) d1min[j] = 3.0e38f;

    const int wid  = tid >> 6;
    const int lane = tid & 63;

    for (int s = 0; s < SS; ++s) {
        const float px = Px[s], py = Py[s], pz = Pz[s];
        float lmin = 3.0e38f;
#pragma unroll
        for (int j = 0; j < 8; ++j) {
            const float dx = px - qx[j];
            const float dy = py - qy[j];
            const float dz = pz - qz[j];
            float d = dx * dx;
            d = fmaf(dy, dy, d);
            d = fmaf(dz, dz, d);
            d1min[j] = fminf(d1min[j], d);
            lmin     = fminf(lmin, d);
        }
#pragma unroll
        for (int off = 32; off > 0; off >>= 1)
            lmin = fminf(lmin, __shfl_down(lmin, off, 64));
        if (lane == 0) wmin[wid][s] = lmin;
    }

#pragma unroll
    for (int j = 0; j < 8; ++j) {
        const int n = tid + j * 256;
        d1[(size_t)(b * NN + n) * MM + m] = d1min[j];
    }

    __syncthreads();
    float v = 0.0f;
    if (tid < SS) {
        v = fminf(fminf(wmin[0][tid], wmin[1][tid]),
                  fminf(wmin[2][tid], wmin[3][tid]));
        if (v >= 1.0e30f) v = 0.0f;
    }
#pragma unroll
    for (int off = 32; off > 0; off >>= 1)
        v += __shfl_down(v, off, 64);
    if (lane == 0) ssum[wid] = v;
    __syncthreads();
    if (tid == 0) d2sum[bm] = ssum[0] + ssum[1] + ssum[2] + ssum[3];
}

__global__ __launch_bounds__(256) void p2p_kernel(
    const float* __restrict__ d1, const float* __restrict__ probs,
    float* __restrict__ partial)
{
    const int gid = blockIdx.x * 256 + threadIdx.x;
    const int b   = gid >> 11;

    float d[16], p[16];
    const float4* dp = (const float4*)(d1 + (size_t)gid * 16);
    float4 v;
    v = dp[0]; d[0]  = v.x; d[1]  = v.y; d[2]  = v.z; d[3]  = v.w;
    v = dp[1]; d[4]  = v.x; d[5]  = v.y; d[6]  = v.z; d[7]  = v.w;
    v = dp[2]; d[8]  = v.x; d[9]  = v.y; d[10] = v.z; d[11] = v.w;
    v = dp[3]; d[12] = v.x; d[13] = v.y; d[14] = v.z; d[15] = v.w;

    const float* pb = probs + b * 16;
#pragma unroll
    for (int k = 0; k < 16; ++k) p[k] = pb[k];

#define CE(i, j)                                              \
    {                                                         \
        const bool c = d[i] > d[j];                           \
        const float td = c ? d[j] : d[i];                     \
        d[j] = c ? d[i] : d[j];  d[i] = td;                   \
        const float tp = c ? p[j] : p[i];                     \
        p[j] = c ? p[i] : p[j];  p[i] = tp;                   \
    }
#pragma unroll
    for (int r = 0; r < 16; ++r) {
        if ((r & 1) == 0) {
            CE(0, 1) CE(2, 3) CE(4, 5) CE(6, 7)
            CE(8, 9) CE(10, 11) CE(12, 13) CE(14, 15)
        } else {
            CE(1, 2) CE(3, 4) CE(5, 6) CE(7, 8)
            CE(9, 10) CE(11, 12) CE(13, 14)
        }
    }
#undef CE

    float acc = 1.0f, sum = 0.0f;
#pragma unroll
    for (int k = 0; k < 16; ++k) {
        sum += d[k] * p[k] * acc;
        acc *= (1.0f - p[k]);
    }

    const int wid  = threadIdx.x >> 6;
    const int lane = threadIdx.x & 63;
    __shared__ float red[4];
#pragma unroll
    for (int off = 32; off > 0; off >>= 1)
        sum += __shfl_down(sum, off, 64);
    if (lane == 0) red[wid] = sum;
    __syncthreads();
    if (threadIdx.x == 0)
        partial[blockIdx.x] = red[0] + red[1] + red[2] + red[3];
}

__global__ __launch_bounds__(256) void final_kernel(
    const float* __restrict__ size_, const float* __restrict__ probs,
    const float* __restrict__ d2sum, const float* __restrict__ partial,
    float* __restrict__ out)
{
    const int tid = threadIdx.x;
    const int b   = tid >> 4;

    __shared__ float  areaSh[256];
    __shared__ double redA[4];
    __shared__ double redB[4];

    const float s0 = size_[tid * 3 + 0];
    const float s1 = size_[tid * 3 + 1];
    const float s2 = size_[tid * 3 + 2];
    const float inner = powf(s0 * s1, 1.6f) * (1.0f / 3.0f)
                      + powf(s0 * s2, 1.6f) * (1.0f / 3.0f)
                      + powf(s1 * s2, 1.6f) * (1.0f / 3.0f);
    const float a = kFourPi * powf(inner, 0.625f);
    areaSh[tid] = a;
    __syncthreads();

    float asum = 0.0f;
#pragma unroll
    for (int mm = 0; mm < 16; ++mm) asum += areaSh[b * 16 + mm];
    const float anorm = 16.0f * a / asum;

    const int wid  = tid >> 6;
    const int lane = tid & 63;

    double t = (double)(d2sum[tid] * (1.0f / 128.0f)) * (double)probs[tid] * (double)anorm;
#pragma unroll
    for (int off = 32; off > 0; off >>= 1)
        t += __shfl_down(t, off, 64);
    if (lane == 0) redA[wid] = t;

    double u = (tid < 128) ? (double)partial[tid] : 0.0;
#pragma unroll
    for (int off = 32; off > 0; off >>= 1)
        u += __shfl_down(u, off, 64);
    if (lane == 0) redB[wid] = u;

    __syncthreads();
    if (tid == 0) {
        const double prim_to_pcl = (redA[0] + redA[1] + redA[2] + redA[3]) / 256.0;
        const double pcl_to_prim = (redB[0] + redB[1] + redB[2] + redB[3]) / 32768.0;
        out[0] = (float)(pcl_to_prim + prim_to_pcl);
        out[1] = (float)pcl_to_prim;
        out[2] = (float)prim_to_pcl;
        out[3] = 0.0f;
    }
}

// ---------------------------------------------------------------------------

extern "C" void kernel_launch(void* const* d_in, const int* in_sizes, int n_in,
                              void* d_out, int out_size, void* d_ws, size_t ws_size,
                              hipStream_t stream) {
    const float* pcl   = (const float*)d_in[0];  // (B,N,M,3)
    const float* prim  = (const float*)d_in[1];  // (B,M,S,3)
    const float* size_ = (const float*)d_in[2];  // (B,M,3)
    const float* probs = (const float*)d_in[3];  // (B,M)
    float* out = (float*)d_out;

    const size_t nBMN = (size_t)BB * MM * NN;           // 524288
    const size_t fast_floats = 3 * nBMN + 4 * nBMN + 1024 + 256;

    if (ws_size >= fast_floats * sizeof(float)) {
        float* pclX    = (float*)d_ws;
        float* pclY    = pclX + nBMN;
        float* pclZ    = pclY + nBMN;
        float* d1part  = pclZ + nBMN;        // [4][256][2048]
        float* d2part  = d1part + 4 * nBMN;  // [4][256]
        float* partial = d2part + 1024;      // [256]

        transpose_kernel<<<dim3(BB, 16), 256, 0, stream>>>(pcl, pclX, pclY, pclZ);
        dist2_kernel<<<dim3(BB * MM, 4), 256, 0, stream>>>(pclX, pclY, pclZ, prim, d1part, d2part);
        p2p2_kernel<<<256, 128, 0, stream>>>(d1part, probs, partial);
        final2_kernel<<<1, 256, 0, stream>>>(size_, probs, d2part, partial, out);
    } else {
        float* d1      = (float*)d_ws;
        float* d2sum   = d1 + nBMN;
        float* partial = d2sum + BB * MM;

        dist_kernel<<<BB * MM, 256, 0, stream>>>(pcl, prim, d1, d2sum);
        p2p_kernel<<<(BB * NN) / 256, 256, 0, stream>>>(d1, probs, partial);
        final_kernel<<<1, 256, 0, stream>>>(size_, probs, d2sum, partial, out);
    }
}